// Round 3
// baseline (190.654 us; speedup 1.0000x reference)
//
#include <hip/hip_runtime.h>
#include <math.h>

constexpr int B = 32, D = 32, T = 16384, N = 128;
constexpr int HALF_T = T / 2;
constexpr float MARG = 2.5e-5f;   // > 3x rigorous |approx - np_exact| bound

// numpy pairwise_sum (n=32): 8 accumulators + ordered combine, squares
// separately rounded. Bit-exact vs np.linalg.norm's sumsq.
__device__ __forceinline__ float np_pairwise32_sq(const float* v) {
#pragma clang fp contract(off)
    float r[8];
    #pragma unroll
    for (int j = 0; j < 8; ++j) r[j] = v[j] * v[j];
    #pragma unroll
    for (int i = 8; i < 32; i += 8) {
        #pragma unroll
        for (int j = 0; j < 8; ++j) r[j] += v[i + j] * v[i + j];
    }
    return ((r[0] + r[1]) + (r[2] + r[3])) + ((r[4] + r[5]) + (r[6] + r[7]));
}

// Exact numpy einsum fold: sequential over d ascending, mul and add
// separately rounded (verified bit-exact in round 2).
__device__ __forceinline__ float np_seq_dot(const float* __restrict__ sn,
                                            const float4* __restrict__ rw) {
#pragma clang fp contract(off)
    float acc = 0.0f;
    #pragma unroll
    for (int k = 0; k < 8; ++k) {
        float4 q = rw[k];
        acc += sn[4 * k + 0] * q.x;
        acc += sn[4 * k + 1] * q.y;
        acc += sn[4 * k + 2] * q.z;
        acc += sn[4 * k + 3] * q.w;
    }
    return acc;
}

// Branchless sorted top-4 insert (strict > : lower index wins ties) + m5
// (max score excluded from the running top-4).
#define INSERT_TRACK(v, n, tv0, tv1, tv2, tv3, ti0, ti1, ti2, ti3, m5)      \
    {                                                                       \
        float old3 = tv3;                                                   \
        bool c0 = (v) > tv0, c1 = (v) > tv1, c2 = (v) > tv2, c3 = (v) > tv3;\
        tv3 = c3 ? (c2 ? tv2 : (v)) : tv3;  ti3 = c3 ? (c2 ? ti2 : (n)) : ti3; \
        tv2 = c2 ? (c1 ? tv1 : (v)) : tv2;  ti2 = c2 ? (c1 ? ti1 : (n)) : ti2; \
        tv1 = c1 ? (c0 ? tv0 : (v)) : tv1;  ti1 = c1 ? (c0 ? ti0 : (n)) : ti1; \
        tv0 = c0 ? (v) : tv0;               ti0 = c0 ? (n) : ti0;           \
        m5 = fmaxf(m5, fminf((v), old3));                                   \
    }

#define INSERT4(v, n, tv0, tv1, tv2, tv3, ti0, ti1, ti2, ti3)               \
    {                                                                       \
        bool c0 = (v) > tv0, c1 = (v) > tv1, c2 = (v) > tv2, c3 = (v) > tv3;\
        tv3 = c3 ? (c2 ? tv2 : (v)) : tv3;  ti3 = c3 ? (c2 ? ti2 : (n)) : ti3; \
        tv2 = c2 ? (c1 ? tv1 : (v)) : tv2;  ti2 = c2 ? (c1 ? ti1 : (n)) : ti2; \
        tv1 = c1 ? (c0 ? tv0 : (v)) : tv1;  ti1 = c1 ? (c0 ? ti0 : (n)) : ti1; \
        tv0 = c0 ? (v) : tv0;               ti0 = c0 ? (n) : ti0;           \
    }

__global__ __launch_bounds__(256) void ve_kernel(
    const float* __restrict__ source,   // [B][D][T]
    const float* __restrict__ tokens,   // [D][N]
    float* __restrict__ out)            // [B][D][T]
{
    __shared__ float rn[N][D];      // normalized refs (np-bit-exact)
    __shared__ float rf[N][D + 1];  // raw refs, +1 pad for the gather

    for (int i = threadIdx.x; i < N * D; i += 256) {
        int d = i >> 7, n = i & (N - 1);
        rf[n][d] = tokens[i];
    }
    __syncthreads();

    if (threadIdx.x < N) {
        int n = threadIdx.x;
        float tq[D];
        #pragma unroll
        for (int d = 0; d < D; ++d) tq[d] = rf[n][d];
        float nrm = sqrtf(np_pairwise32_sq(tq));
        #pragma unroll
        for (int d = 0; d < D; ++d) rn[n][d] = tq[d] / nrm;
    }
    __syncthreads();

    // Two queries per thread: (b, t) and (b, t + T/2); both coalesced.
    int gid = blockIdx.x * 256 + threadIdx.x;       // [0, B*T/2)
    int b = gid >> 13;                               // / (T/2)
    int t = gid & (HALF_T - 1);

    const float* src0 = source + (size_t)b * D * T + t;

    float sn0[D], sn1[D];
    {
        float s0[D], s1[D];
        #pragma unroll
        for (int d = 0; d < D; ++d) {
            s0[d] = src0[(size_t)d * T];
            s1[d] = src0[(size_t)d * T + HALF_T];
        }
        float n0 = sqrtf(np_pairwise32_sq(s0));
        float n1 = sqrtf(np_pairwise32_sq(s1));
        #pragma unroll
        for (int d = 0; d < D; ++d) { sn0[d] = s0[d] / n0; sn1[d] = s1[d] / n1; }
    }

    float av0 = -INFINITY, av1 = -INFINITY, av2 = -INFINITY, av3 = -INFINITY;
    int   ai0 = 0, ai1 = 0, ai2 = 0, ai3 = 0;
    float bv0 = -INFINITY, bv1 = -INFINITY, bv2 = -INFINITY, bv3 = -INFINITY;
    int   bi0 = 0, bi1 = 0, bi2 = 0, bi3 = 0;
    float m5a = -INFINITY, m5b = -INFINITY;

    for (int n = 0; n < N; ++n) {
        const float4* rw = reinterpret_cast<const float4*>(&rn[n][0]);
        // Approx scores: FMA-contracted fold, 2 independent chains each.
        float a_e = 0.f, a_o = 0.f, b_e = 0.f, b_o = 0.f;
        #pragma unroll
        for (int k = 0; k < 8; ++k) {
            float4 q = rw[k];
            a_e = __builtin_fmaf(sn0[4 * k + 0], q.x, a_e);
            a_o = __builtin_fmaf(sn0[4 * k + 1], q.y, a_o);
            a_e = __builtin_fmaf(sn0[4 * k + 2], q.z, a_e);
            a_o = __builtin_fmaf(sn0[4 * k + 3], q.w, a_o);
            b_e = __builtin_fmaf(sn1[4 * k + 0], q.x, b_e);
            b_o = __builtin_fmaf(sn1[4 * k + 1], q.y, b_o);
            b_e = __builtin_fmaf(sn1[4 * k + 2], q.z, b_e);
            b_o = __builtin_fmaf(sn1[4 * k + 3], q.w, b_o);
        }
        float va = a_e + a_o;
        float vb = b_e + b_o;
        INSERT_TRACK(va, n, av0, av1, av2, av3, ai0, ai1, ai2, ai3, m5a);
        INSERT_TRACK(vb, n, bv0, bv1, bv2, bv3, bi0, bi1, bi2, bi3, m5b);
    }

    // Rescue: 4/5 boundary ambiguous under fp rounding differences ->
    // recompute this query with the bit-exact numpy fold.
    if (av3 - m5a <= MARG) {
        av0 = av1 = av2 = av3 = -INFINITY;
        ai0 = ai1 = ai2 = ai3 = 0;
        for (int n = 0; n < N; ++n) {
            float v = np_seq_dot(sn0, reinterpret_cast<const float4*>(&rn[n][0]));
            INSERT4(v, n, av0, av1, av2, av3, ai0, ai1, ai2, ai3);
        }
    }
    if (bv3 - m5b <= MARG) {
        bv0 = bv1 = bv2 = bv3 = -INFINITY;
        bi0 = bi1 = bi2 = bi3 = 0;
        for (int n = 0; n < N; ++n) {
            float v = np_seq_dot(sn1, reinterpret_cast<const float4*>(&rn[n][0]));
            INSERT4(v, n, bv0, bv1, bv2, bv3, bi0, bi1, bi2, bi3);
        }
    }

    // Gather + mean (sum order only perturbs ~1 ulp; threshold is 5.9e-2).
    float* dst = out + (size_t)b * D * T + t;
    #pragma unroll
    for (int d = 0; d < D; ++d) {
        float sa = ((rf[ai0][d] + rf[ai1][d]) + rf[ai2][d]) + rf[ai3][d];
        float sb = ((rf[bi0][d] + rf[bi1][d]) + rf[bi2][d]) + rf[bi3][d];
        dst[(size_t)d * T] = sa * 0.25f;
        dst[(size_t)d * T + HALF_T] = sb * 0.25f;
    }
}

extern "C" void kernel_launch(void* const* d_in, const int* in_sizes, int n_in,
                              void* d_out, int out_size, void* d_ws, size_t ws_size,
                              hipStream_t stream) {
    const float* source = (const float*)d_in[0];
    const float* tokens = (const float*)d_in[1];
    float* out = (float*)d_out;

    dim3 grid((B * T / 2) / 256), block(256);
    ve_kernel<<<grid, block, 0, stream>>>(source, tokens, out);
}

// Round 4
// 158.248 us; speedup vs baseline: 1.2048x; 1.2048x over previous
//
#include <hip/hip_runtime.h>
#include <math.h>

constexpr int B = 32, D = 32, T = 16384, N = 128;
constexpr float MARG = 2e-5f;   // rel. margin on 4/5 gap; 2.3x worst-case bound

// numpy pairwise_sum (n=32): 8 accumulators + ordered combine, squares
// separately rounded. Bit-exact vs np.linalg.norm's sumsq (validated R2).
__device__ __forceinline__ float np_pairwise32_sq(const float* v) {
#pragma clang fp contract(off)
    float r[8];
    #pragma unroll
    for (int j = 0; j < 8; ++j) r[j] = v[j] * v[j];
    #pragma unroll
    for (int i = 8; i < 32; i += 8) {
        #pragma unroll
        for (int j = 0; j < 8; ++j) r[j] += v[i + j] * v[i + j];
    }
    return ((r[0] + r[1]) + (r[2] + r[3])) + ((r[4] + r[5]) + (r[6] + r[7]));
}

// Exact numpy einsum fold: sequential over d ascending, mul and add
// separately rounded (validated bit-exact in R2).
__device__ __forceinline__ float np_seq_dot(const float* __restrict__ sn,
                                            const float4* __restrict__ rw) {
#pragma clang fp contract(off)
    float acc = 0.0f;
    #pragma unroll
    for (int k = 0; k < 8; ++k) {
        float4 q = rw[k];
        acc += sn[4 * k + 0] * q.x;
        acc += sn[4 * k + 1] * q.y;
        acc += sn[4 * k + 2] * q.z;
        acc += sn[4 * k + 3] * q.w;
    }
    return acc;
}

// Branchless sorted top-4 insert (strict > : lower index wins ties).
#define INSERT4(v, n)                                                        \
    {                                                                        \
        bool c0 = (v) > tv0, c1 = (v) > tv1, c2 = (v) > tv2, c3 = (v) > tv3; \
        tv3 = c3 ? (c2 ? tv2 : (v)) : tv3;  ti3 = c3 ? (c2 ? ti2 : (n)) : ti3; \
        tv2 = c2 ? (c1 ? tv1 : (v)) : tv2;  ti2 = c2 ? (c1 ? ti1 : (n)) : ti2; \
        tv1 = c1 ? (c0 ? tv0 : (v)) : tv1;  ti1 = c1 ? (c0 ? ti0 : (n)) : ti1; \
        tv0 = c0 ? (v) : tv0;               ti0 = c0 ? (n) : ti0;            \
    }

// Same, plus m5 = running max of everything that fell out of the top-4.
#define INSERT_TRACK(v, n)                                                   \
    {                                                                        \
        float old3 = tv3;                                                    \
        INSERT4(v, n);                                                       \
        m5 = fmaxf(m5, fminf((v), old3));                                    \
    }

__global__ __launch_bounds__(256) void ve_kernel(
    const float* __restrict__ source,   // [B][D][T]
    const float* __restrict__ tokens,   // [D][N]
    float* __restrict__ out)            // [B][D][T]
{
    __shared__ float rn[N][D];      // np-bit-exact normalized refs
    __shared__ float rf[N][D + 1];  // raw refs, +1 pad for the gather

    for (int i = threadIdx.x; i < N * D; i += 256) {
        int d = i >> 7, n = i & (N - 1);
        rf[n][d] = tokens[i];
    }
    __syncthreads();

    if (threadIdx.x < N) {
        int n = threadIdx.x;
        float tq[D];
        #pragma unroll
        for (int d = 0; d < D; ++d) tq[d] = rf[n][d];
        float nrm = sqrtf(np_pairwise32_sq(tq));
        #pragma unroll
        for (int d = 0; d < D; ++d) rn[n][d] = tq[d] / nrm;
    }
    __syncthreads();

    int gid = blockIdx.x * 256 + threadIdx.x;
    int b = gid >> 14, t = gid & (T - 1);

    const float* src = source + (size_t)b * D * T + t;
    float s[D];
    #pragma unroll
    for (int d = 0; d < D; ++d) s[d] = src[(size_t)d * T];

    // Query norm only for the margin scale (ordering is norm-invariant).
    float nrm = sqrtf(np_pairwise32_sq(s));

    float tv0 = -INFINITY, tv1 = -INFINITY, tv2 = -INFINITY, tv3 = -INFINITY;
    int   ti0 = 0, ti1 = 0, ti2 = 0, ti3 = 0;
    float m5 = -INFINITY;

    for (int n = 0; n < N; ++n) {
        const float4* rw = reinterpret_cast<const float4*>(&rn[n][0]);
        // Approx raw dot: FMA fold, two independent chains.
        float a_e = 0.f, a_o = 0.f;
        #pragma unroll
        for (int k = 0; k < 8; ++k) {
            float4 q = rw[k];
            a_e = __builtin_fmaf(s[4 * k + 0], q.x, a_e);
            a_o = __builtin_fmaf(s[4 * k + 1], q.y, a_o);
            a_e = __builtin_fmaf(s[4 * k + 2], q.z, a_e);
            a_o = __builtin_fmaf(s[4 * k + 3], q.w, a_o);
        }
        float v = a_e + a_o;
        INSERT_TRACK(v, n);
    }

    // 4/5 boundary ambiguous under rounding differences -> bit-exact re-walk.
    if (tv3 - m5 <= MARG * nrm) {
        float sn[D];
        #pragma unroll
        for (int d = 0; d < D; ++d) sn[d] = s[d] / nrm;   // IEEE div, np-exact
        tv0 = tv1 = tv2 = tv3 = -INFINITY;
        ti0 = ti1 = ti2 = ti3 = 0;
        for (int n = 0; n < N; ++n) {
            float v = np_seq_dot(sn, reinterpret_cast<const float4*>(&rn[n][0]));
            INSERT4(v, n);
        }
    }

    // Gather + mean in top-k order; /4 exact via *0.25.
    float* dst = out + (size_t)b * D * T + t;
    #pragma unroll
    for (int d = 0; d < D; ++d) {
        float sum = ((rf[ti0][d] + rf[ti1][d]) + rf[ti2][d]) + rf[ti3][d];
        dst[(size_t)d * T] = sum * 0.25f;
    }
}

extern "C" void kernel_launch(void* const* d_in, const int* in_sizes, int n_in,
                              void* d_out, int out_size, void* d_ws, size_t ws_size,
                              hipStream_t stream) {
    const float* source = (const float*)d_in[0];
    const float* tokens = (const float*)d_in[1];
    float* out = (float*)d_out;

    dim3 grid((B * T) / 256), block(256);
    ve_kernel<<<grid, block, 0, stream>>>(source, tokens, out);
}

// Round 5
// 155.574 us; speedup vs baseline: 1.2255x; 1.0172x over previous
//
#include <hip/hip_runtime.h>
#include <math.h>

typedef float f32x2 __attribute__((ext_vector_type(2)));

constexpr int B = 32, D = 32, T = 16384, N = 128;
constexpr float MARG = 2e-5f;   // rel. 4/5-gap margin; ~2.9x worst-case bound

// numpy pairwise_sum (n=32): 8 accumulators + ordered combine, squares
// separately rounded. Bit-exact vs np.linalg.norm sumsq (validated R2).
__device__ __forceinline__ float np_pairwise32_sq(const float* v) {
#pragma clang fp contract(off)
    float r[8];
    #pragma unroll
    for (int j = 0; j < 8; ++j) r[j] = v[j] * v[j];
    #pragma unroll
    for (int i = 8; i < 32; i += 8) {
        #pragma unroll
        for (int j = 0; j < 8; ++j) r[j] += v[i + j] * v[i + j];
    }
    return ((r[0] + r[1]) + (r[2] + r[3])) + ((r[4] + r[5]) + (r[6] + r[7]));
}

// Same pairwise sum over f32x2-packed storage (element e -> v[e>>1], e&1).
__device__ __forceinline__ float np_pairwise32_sq2(const f32x2* v) {
#pragma clang fp contract(off)
    float r[8];
    #pragma unroll
    for (int j = 0; j < 8; ++j) {
        float x = (j & 1) ? v[j >> 1].y : v[j >> 1].x;
        r[j] = x * x;
    }
    #pragma unroll
    for (int i = 8; i < 32; i += 8) {
        #pragma unroll
        for (int j = 0; j < 8; ++j) {
            int e = i + j;
            float x = (e & 1) ? v[e >> 1].y : v[e >> 1].x;
            r[j] += x * x;
        }
    }
    return ((r[0] + r[1]) + (r[2] + r[3])) + ((r[4] + r[5]) + (r[6] + r[7]));
}

// Exact numpy einsum fold (validated bit-exact R2): sequential d ascending,
// mul and add separately rounded.
__device__ __forceinline__ float np_seq_dot_g(const float* __restrict__ sn,
                                              const float4* __restrict__ rw) {
#pragma clang fp contract(off)
    float acc = 0.0f;
    #pragma unroll
    for (int k = 0; k < 8; ++k) {
        float4 q = rw[k];
        acc += sn[4 * k + 0] * q.x;
        acc += sn[4 * k + 1] * q.y;
        acc += sn[4 * k + 2] * q.z;
        acc += sn[4 * k + 3] * q.w;
    }
    return acc;
}

// Pre-kernel: bit-exact normalized refs -> d_ws (so the main loop can read
// them as wave-uniform scalar loads instead of LDS).
__global__ void norm_tokens_kernel(const float* __restrict__ tokens,
                                   float* __restrict__ rn_g) {
    int n = threadIdx.x;
    if (n < N) {
        float tq[D];
        #pragma unroll
        for (int d = 0; d < D; ++d) tq[d] = tokens[d * N + n];
        float nrm = sqrtf(np_pairwise32_sq(tq));
        #pragma unroll
        for (int d = 0; d < D; ++d) rn_g[n * D + d] = tq[d] / nrm;
    }
}

// Sorted top-4 insert: values via max/med3 (4 instrs), indices via cndmask.
// Strict > keeps the earlier (lower) index on exact ties (stable, = jax).
#define INSERT_STEP(v, n)                                                    \
    {                                                                        \
        bool c0 = (v) > t0, c1 = (v) > t1, c2 = (v) > t2, c3 = (v) > t3;     \
        float nt0 = fmaxf(t0, (v));                                          \
        float nt1 = __builtin_amdgcn_fmed3f((v), t1, t0);                    \
        float nt2 = __builtin_amdgcn_fmed3f((v), t2, t1);                    \
        float nt3 = __builtin_amdgcn_fmed3f((v), t3, t2);                    \
        int ni0 = c0 ? (n) : i0;                                             \
        int ni1 = c1 ? (c0 ? i0 : (n)) : i1;                                 \
        int ni2 = c2 ? (c1 ? i1 : (n)) : i2;                                 \
        int ni3 = c3 ? (c2 ? i2 : (n)) : i3;                                 \
        t0 = nt0; t1 = nt1; t2 = nt2; t3 = nt3;                              \
        i0 = ni0; i1 = ni1; i2 = ni2; i3 = ni3;                              \
    }

__global__ __launch_bounds__(256) void ve_kernel(
    const float* __restrict__ source,   // [B][D][T]
    const float* __restrict__ rn_g,     // [N][D] normalized (pre-kernel)
    const float* __restrict__ tokens,   // [D][N] raw
    float* __restrict__ out)            // [B][D][T]
{
    __shared__ float rf[N][D + 1];      // raw refs for the gather only

    for (int i = threadIdx.x; i < N * D; i += 256) {
        int d = i >> 7, n = i & (N - 1);
        rf[n][d] = tokens[i];
    }
    __syncthreads();

    int gid = blockIdx.x * 256 + threadIdx.x;
    int b = gid >> 14, t = gid & (T - 1);

    const float* src = source + (size_t)b * D * T + t;
    f32x2 s2[16];
    #pragma unroll
    for (int k = 0; k < 16; ++k) {
        s2[k].x = src[(size_t)(2 * k) * T];
        s2[k].y = src[(size_t)(2 * k + 1) * T];
    }
    float nrm = sqrtf(np_pairwise32_sq2(s2));   // np-exact query norm

    float t0 = -INFINITY, t1 = -INFINITY, t2 = -INFINITY, t3 = -INFINITY;
    float m5 = -INFINITY;
    int i0 = 0, i1 = 0, i2 = 0, i3 = 0;

    const f32x2* rn2 = (const f32x2*)rn_g;
    #pragma unroll 2
    for (int n = 0; n < N; ++n) {
        const f32x2* r2 = rn2 + (n << 4);   // wave-uniform address
        f32x2 e = {0.f, 0.f}, o = {0.f, 0.f};
        #pragma unroll
        for (int k = 0; k < 16; k += 2) {   // contract(fast) -> v_pk_fma_f32
            e += s2[k] * r2[k];
            o += s2[k + 1] * r2[k + 1];
        }
        f32x2 h = e + o;
        float v = h.x + h.y;                // approx raw dot

        m5 = fmaxf(m5, fminf(v, t3));       // running max of non-top-4
        INSERT_STEP(v, n);
    }

    // Ambiguous 4/5 boundary under rounding differences -> bit-exact re-walk.
    if (t3 - m5 <= MARG * nrm) {
        float sn[32];
        #pragma unroll
        for (int k = 0; k < 16; ++k) {
            sn[2 * k]     = s2[k].x / nrm;  // IEEE div, matches np
            sn[2 * k + 1] = s2[k].y / nrm;
        }
        t0 = t1 = t2 = t3 = -INFINITY;
        i0 = i1 = i2 = i3 = 0;
        for (int n = 0; n < N; ++n) {
            float v = np_seq_dot_g(sn, (const float4*)rn_g + (n << 3));
            INSERT_STEP(v, n);
        }
    }

    // Gather + mean in top-k order; /4 exact via *0.25.
    float* dst = out + (size_t)b * D * T + t;
    #pragma unroll
    for (int d = 0; d < D; ++d) {
        float sum = ((rf[i0][d] + rf[i1][d]) + rf[i2][d]) + rf[i3][d];
        dst[(size_t)d * T] = sum * 0.25f;
    }
}

extern "C" void kernel_launch(void* const* d_in, const int* in_sizes, int n_in,
                              void* d_out, int out_size, void* d_ws, size_t ws_size,
                              hipStream_t stream) {
    const float* source = (const float*)d_in[0];
    const float* tokens = (const float*)d_in[1];
    float* out = (float*)d_out;
    float* rn_g = (float*)d_ws;               // 16 KB scratch for normalized refs

    norm_tokens_kernel<<<1, 128, 0, stream>>>(tokens, rn_g);
    ve_kernel<<<(B * T) / 256, 256, 0, stream>>>(source, rn_g, tokens, out);
}